// Round 1
// baseline (680.183 us; speedup 1.0000x reference)
//
#include <hip/hip_runtime.h>
#include <math.h>

#define D 128

typedef __attribute__((ext_vector_type(8))) short short8;
typedef __attribute__((ext_vector_type(4))) float floatx4;
typedef __attribute__((ext_vector_type(2))) _Float16 half2v;
typedef __attribute__((ext_vector_type(8))) _Float16 half8;

// ---------------- graph preprocessing ----------------

__global__ __launch_bounds__(256) void k_zero(int* __restrict__ p, int n) {
  int i = blockIdx.x * 256 + threadIdx.x;
  if (i < n) p[i] = 0;
}

// Octant-partitioned histogram: blocks with (blockIdx & 7) == k handle only
// dst in octant k. Under round-robin blockIdx->XCD dispatch, each octant's
// 50 KB counts window stays in ONE XCD's L2 -> no cross-XCD atomic-line
// ping-pong. Each octant group rescans the full dst array (sequential,
// L3-resident) - cheap currency vs dirty-line bouncing.
__global__ __launch_bounds__(256) void k_hist(const int* __restrict__ dst,
                                              int* __restrict__ counts, int E, int N) {
  int oct = blockIdx.x & 7;
  int cid = blockIdx.x >> 3;
  int nch = gridDim.x >> 3;
  int n8 = (N + 7) >> 3;
  int lo = oct * n8;
  int hi = lo + n8 < N ? lo + n8 : N;
  int per = (E + nch - 1) / nch;
  int e0 = cid * per;
  int e1 = e0 + per < E ? e0 + per : E;
  for (int e = e0 + (int)threadIdx.x; e < e1; e += 256) {
    int d = dst[e];
    if (d >= lo && d < hi) atomicAdd(&counts[d], 1);
  }
}

__global__ __launch_bounds__(256) void k_scan1(const int* __restrict__ in,
                                               int* __restrict__ out,
                                               int* __restrict__ bsum, int n) {
  __shared__ int sd[256];
  int tid = threadIdx.x;
  int base = blockIdx.x * 1024 + tid * 4;
  int v0 = 0, v1 = 0, v2 = 0, v3 = 0;
  if (base + 3 < n) {
    int4 t = *(const int4*)(in + base);
    v0 = t.x; v1 = t.y; v2 = t.z; v3 = t.w;
  } else {
    if (base     < n) v0 = in[base];
    if (base + 1 < n) v1 = in[base + 1];
    if (base + 2 < n) v2 = in[base + 2];
    if (base + 3 < n) v3 = in[base + 3];
  }
  int s = v0 + v1 + v2 + v3;
  sd[tid] = s;
  __syncthreads();
  for (int off = 1; off < 256; off <<= 1) {
    int t = (tid >= off) ? sd[tid - off] : 0;
    __syncthreads();
    sd[tid] += t;
    __syncthreads();
  }
  int incl = sd[tid];
  int excl = incl - s;
  if (tid == 255) bsum[blockIdx.x] = incl;
  int r = excl;
  if (base     < n) out[base]     = r; r += v0;
  if (base + 1 < n) out[base + 1] = r; r += v1;
  if (base + 2 < n) out[base + 2] = r; r += v2;
  if (base + 3 < n) out[base + 3] = r;
}

__global__ __launch_bounds__(256) void k_scan2(int* __restrict__ bsum, int nb) {
  __shared__ int sd[256];
  int tid = threadIdx.x;
  int v = (tid < nb) ? bsum[tid] : 0;
  sd[tid] = v;
  __syncthreads();
  for (int off = 1; off < 256; off <<= 1) {
    int t = (tid >= off) ? sd[tid - off] : 0;
    __syncthreads();
    sd[tid] += t;
    __syncthreads();
  }
  int excl = sd[tid] - v;
  if (tid < nb) bsum[tid] = excl;
}

__global__ __launch_bounds__(256) void k_finish(int* __restrict__ rowptr,
                                                int* __restrict__ cursor,
                                                float* __restrict__ dis,
                                                const int* __restrict__ counts,
                                                const int* __restrict__ bsum, int n) {
  int i = blockIdx.x * 256 + threadIdx.x;
  if (i < n) {
    int r = rowptr[i] + bsum[i >> 10];
    rowptr[i] = r;
    cursor[i] = r;
    dis[i] = rsqrtf((float)(counts[i] + 1));
  }
}

// Octant-partitioned CSR fill. Same partitioning as k_hist: all scattered
// cpack writes (and cursor atomics) for one dst octant come from one XCD,
// so the ~1.6 MB CSR window accumulates its avg-8-writes-per-line in that
// XCD's L2 before a single writeback. Kills the measured 8x write
// amplification (WRITE_SIZE 101.5 MB ~= E * 64 B -> ~payload-sized).
__global__ __launch_bounds__(256) void k_fill(const int* __restrict__ src,
                                              const int* __restrict__ dst,
                                              int* __restrict__ cursor,
                                              const float* __restrict__ dis,
                                              int2* __restrict__ cpack, int E, int N) {
  int oct = blockIdx.x & 7;
  int cid = blockIdx.x >> 3;
  int nch = gridDim.x >> 3;
  int n8 = (N + 7) >> 3;
  int lo = oct * n8;
  int hi = lo + n8 < N ? lo + n8 : N;
  int per = (E + nch - 1) / nch;
  int e0 = cid * per;
  int e1 = e0 + per < E ? e0 + per : E;
  for (int e = e0 + (int)threadIdx.x; e < e1; e += 256) {
    int d = dst[e];
    int s = src[e];  // unconditional: ~88% of src lines have a match anyway
    if (d >= lo && d < hi) {
      int pos = atomicAdd(&cursor[d], 1);
      float nw = dis[s] * dis[d];
      cpack[pos] = make_int2(s, __float_as_int(nw));
    }
  }
}

// ---------------- weight pre-split (once per call) ----------------
// 128x128 weights -> image [c][k]: hi/lo bf16 of W[k][c].
// Wm2 (128x40, padded 48 cols) -> image [c][k]: hi/lo of Wm2[k][c].

__device__ __forceinline__ short f2bf(float v) {
  unsigned u = __float_as_uint(v);
  unsigned r = (u + 0x7FFFu + ((u >> 16) & 1u)) >> 16;
  return (short)r;
}
__device__ __forceinline__ float bf2f(short s) {
  return __uint_as_float(((unsigned)(unsigned short)s) << 16);
}

__global__ __launch_bounds__(256) void k_prep(const float* __restrict__ W1,
                                              const float* __restrict__ W2,
                                              const float* __restrict__ W3,
                                              const float* __restrict__ Wm1,
                                              const float* __restrict__ Wm2,
                                              short* __restrict__ wsplit,
                                              short* __restrict__ w2hi,
                                              short* __restrict__ w2lo) {
  int idx = blockIdx.x * 256 + threadIdx.x;
  if (idx < 65536) {
    int w = idx >> 14;            // which weight
    int rem = idx & 16383;        // c*128 + k
    int c = rem >> 7, k = rem & 127;
    const float* Ws = (w == 0) ? W1 : (w == 1) ? W2 : (w == 2) ? W3 : Wm1;
    float v = Ws[k * D + c];
    short hi = f2bf(v);
    short lo = f2bf(v - bf2f(hi));
    wsplit[(size_t)w * 32768 + rem] = hi;
    wsplit[(size_t)w * 32768 + 16384 + rem] = lo;
  } else if (idx < 65536 + 6144) {
    int i2 = idx - 65536;         // c*128 + k, c in 0..47
    int c = i2 >> 7, k = i2 & 127;
    float v = (c < 40) ? Wm2[k * 40 + c] : 0.f;
    short hi = f2bf(v);
    short lo = f2bf(v - bf2f(hi));
    w2hi[i2] = hi;
    w2lo[i2] = lo;
  }
}

// ---------------- bf16-split MFMA GEMM: Y = X @ W (+bias, +ELU) ----------------
// B staged in LDS (padded stride 72, 16B-aligned rows) per half-K.
// A: amode=0 fp32 rows; amode=2 fp16 rows (exact hi/lo split in-kernel).
// 3-product reconstruction: hi*hi + lo*hi + hi*lo.
// Output: fp16 rows (256B).

__device__ __forceinline__ float elu1(float x) {
  return x > 0.f ? x : (expf(x) - 1.f);
}

__global__ __launch_bounds__(256, 2) void k_gemm(const float* __restrict__ Xf,
                                                 const _Float16* __restrict__ Xh,
                                                 const short* __restrict__ Whi,
                                                 const short* __restrict__ Wlo,
                                                 const float* __restrict__ bias,
                                                 _Float16* __restrict__ Yh,
                                                 int n, int act, int amode) {
  __shared__ short wthi[128 * 72];  // [c][kk-half], padded stride 72 (144B, 16B-aligned)
  __shared__ short wtlo[128 * 72];

  int tid = threadIdx.x;
  int wave = tid >> 6, lane = tid & 63;
  int q = lane >> 4, r = lane & 15;

  long rowbase = (long)blockIdx.x * 128 + wave * 32;
  long row0 = rowbase + r;
  long row1 = rowbase + 16 + r;
  long rc0 = row0 < n ? row0 : (n - 1);
  long rc1 = row1 < n ? row1 : (n - 1);

  floatx4 acc[2][8];
#pragma unroll
  for (int rt = 0; rt < 2; rt++)
#pragma unroll
    for (int ct = 0; ct < 8; ct++) acc[rt][ct] = (floatx4){0.f, 0.f, 0.f, 0.f};

  for (int h = 0; h < 2; h++) {
    __syncthreads();
    // stage half-K of pre-split W images into padded LDS
#pragma unroll
    for (int i = 0; i < 4; i++) {
      int cs = i * 256 + tid;           // 1024 chunks of 8 shorts
      int c = cs >> 3, o = (cs & 7) * 8;
      *(short8*)&wthi[c * 72 + o] = *(const short8*)&Whi[c * D + h * 64 + o];
      *(short8*)&wtlo[c * 72 + o] = *(const short8*)&Wlo[c * D + h * 64 + o];
    }
    __syncthreads();

#pragma unroll
    for (int ks2 = 0; ks2 < 2; ks2++) {
      int ksg = h * 2 + ks2;            // global k-step 0..3
      int kk0 = ks2 * 32;
      short8 ahi0, alo0, ahi1, alo1;
      if (amode == 2) {
        half8 a0 = *(const half8*)(Xh + rc0 * D + ksg * 32 + q * 8);
        half8 a1 = *(const half8*)(Xh + rc1 * D + ksg * 32 + q * 8);
#pragma unroll
        for (int j = 0; j < 8; j++) {
          float v = (float)a0[j];
          short hi = f2bf(v);
          ahi0[j] = hi; alo0[j] = f2bf(v - bf2f(hi));
          v = (float)a1[j];
          hi = f2bf(v);
          ahi1[j] = hi; alo1[j] = f2bf(v - bf2f(hi));
        }
      } else {
        const floatx4* x0 = (const floatx4*)(Xf + rc0 * D);
        const floatx4* x1 = (const floatx4*)(Xf + rc1 * D);
        int xi = ksg * 8 + q * 2;
        floatx4 a0 = x0[xi], a0b = x0[xi + 1];
        floatx4 a1 = x1[xi], a1b = x1[xi + 1];
#pragma unroll
        for (int j = 0; j < 4; j++) {
          float v = a0[j];  short hi = f2bf(v);
          ahi0[j] = hi; alo0[j] = f2bf(v - bf2f(hi));
          v = a0b[j]; hi = f2bf(v);
          ahi0[4 + j] = hi; alo0[4 + j] = f2bf(v - bf2f(hi));
          v = a1[j];  hi = f2bf(v);
          ahi1[j] = hi; alo1[j] = f2bf(v - bf2f(hi));
          v = a1b[j]; hi = f2bf(v);
          ahi1[4 + j] = hi; alo1[4 + j] = f2bf(v - bf2f(hi));
        }
      }
#pragma unroll
      for (int ct = 0; ct < 8; ct++) {
        int c = ct * 16 + r;
        short8 bh = *(const short8*)&wthi[c * 72 + kk0 + q * 8];
        short8 bl = *(const short8*)&wtlo[c * 72 + kk0 + q * 8];
        acc[0][ct] = __builtin_amdgcn_mfma_f32_16x16x32_bf16(ahi0, bh, acc[0][ct], 0, 0, 0);
        acc[0][ct] = __builtin_amdgcn_mfma_f32_16x16x32_bf16(alo0, bh, acc[0][ct], 0, 0, 0);
        acc[0][ct] = __builtin_amdgcn_mfma_f32_16x16x32_bf16(ahi0, bl, acc[0][ct], 0, 0, 0);
        acc[1][ct] = __builtin_amdgcn_mfma_f32_16x16x32_bf16(ahi1, bh, acc[1][ct], 0, 0, 0);
        acc[1][ct] = __builtin_amdgcn_mfma_f32_16x16x32_bf16(alo1, bh, acc[1][ct], 0, 0, 0);
        acc[1][ct] = __builtin_amdgcn_mfma_f32_16x16x32_bf16(ahi1, bl, acc[1][ct], 0, 0, 0);
      }
    }
  }

  // epilogue: C/D layout col = lane&15, row = q*4 + reg; fp16 out
#pragma unroll
  for (int rt = 0; rt < 2; rt++) {
#pragma unroll
    for (int i = 0; i < 4; i++) {
      long row = rowbase + rt * 16 + q * 4 + i;
      if (row < n) {
#pragma unroll
        for (int ct = 0; ct < 8; ct++) {
          int col = ct * 16 + r;
          float v = acc[rt][ct][i];
          if (bias) v += bias[col];
          if (act == 1) v = elu1(v);
          Yh[row * D + col] = (_Float16)v;
        }
      }
    }
  }
}

// ---------------- aggregation ----------------
// Y[d] = relu(sum_{e: dst=d} T[src]*norm + T[d]*dis[d]^2 + b)
// one wave per node; fp16 gather rows (256B), fp32 accumulate, unroll x8.
// Output: fp16 row; optionally fp32 too (emb, layer 3).

__global__ __launch_bounds__(256) void k_agg(const _Float16* __restrict__ T,
                                             const int* __restrict__ rowptr,
                                             const int* __restrict__ counts,
                                             const int2* __restrict__ cpack,
                                             const float* __restrict__ dis,
                                             const float* __restrict__ bias,
                                             _Float16* __restrict__ Yh,
                                             float* __restrict__ Yf, int n) {
  int node = blockIdx.x * 4 + (threadIdx.x >> 6);
  if (node >= n) return;
  int lane = threadIdx.x & 63;
  const half2v* T2 = (const half2v*)T;

  int s = rowptr[node];
  int e = s + counts[node];
  float dv = dis[node];
  half2v t = T2[(size_t)node * 64 + lane];
  float ax = (float)t[0] * (dv * dv), ay = (float)t[1] * (dv * dv);
  float bx2 = 0.f, by2 = 0.f, cx = 0.f, cy = 0.f, dx = 0.f, dy = 0.f;

  int j = s;
  for (; j + 7 < e; j += 8) {
    int2 m0 = cpack[j],     m1 = cpack[j + 1], m2 = cpack[j + 2], m3 = cpack[j + 3];
    int2 m4 = cpack[j + 4], m5 = cpack[j + 5], m6 = cpack[j + 6], m7 = cpack[j + 7];
    half2v v0 = T2[(size_t)m0.x * 64 + lane];
    half2v v1 = T2[(size_t)m1.x * 64 + lane];
    half2v v2 = T2[(size_t)m2.x * 64 + lane];
    half2v v3 = T2[(size_t)m3.x * 64 + lane];
    half2v v4 = T2[(size_t)m4.x * 64 + lane];
    half2v v5 = T2[(size_t)m5.x * 64 + lane];
    half2v v6 = T2[(size_t)m6.x * 64 + lane];
    half2v v7 = T2[(size_t)m7.x * 64 + lane];
    float n0 = __int_as_float(m0.y), n1 = __int_as_float(m1.y);
    float n2 = __int_as_float(m2.y), n3 = __int_as_float(m3.y);
    float n4 = __int_as_float(m4.y), n5 = __int_as_float(m5.y);
    float n6 = __int_as_float(m6.y), n7 = __int_as_float(m7.y);
    ax  += (float)v0[0] * n0; ay  += (float)v0[1] * n0;
    bx2 += (float)v1[0] * n1; by2 += (float)v1[1] * n1;
    cx  += (float)v2[0] * n2; cy  += (float)v2[1] * n2;
    dx  += (float)v3[0] * n3; dy  += (float)v3[1] * n3;
    ax  += (float)v4[0] * n4; ay  += (float)v4[1] * n4;
    bx2 += (float)v5[0] * n5; by2 += (float)v5[1] * n5;
    cx  += (float)v6[0] * n6; cy  += (float)v6[1] * n6;
    dx  += (float)v7[0] * n7; dy  += (float)v7[1] * n7;
  }
  for (; j + 3 < e; j += 4) {
    int2 m0 = cpack[j], m1 = cpack[j + 1], m2 = cpack[j + 2], m3 = cpack[j + 3];
    half2v v0 = T2[(size_t)m0.x * 64 + lane];
    half2v v1 = T2[(size_t)m1.x * 64 + lane];
    half2v v2 = T2[(size_t)m2.x * 64 + lane];
    half2v v3 = T2[(size_t)m3.x * 64 + lane];
    float n0 = __int_as_float(m0.y), n1 = __int_as_float(m1.y);
    float n2 = __int_as_float(m2.y), n3 = __int_as_float(m3.y);
    ax  += (float)v0[0] * n0; ay  += (float)v0[1] * n0;
    bx2 += (float)v1[0] * n1; by2 += (float)v1[1] * n1;
    cx  += (float)v2[0] * n2; cy  += (float)v2[1] * n2;
    dx  += (float)v3[0] * n3; dy  += (float)v3[1] * n3;
  }
  for (; j < e; ++j) {
    int2 m0 = cpack[j];
    half2v v0 = T2[(size_t)m0.x * 64 + lane];
    float n0 = __int_as_float(m0.y);
    ax += (float)v0[0] * n0; ay += (float)v0[1] * n0;
  }

  const float2* b2p = (const float2*)bias;
  float2 bb = b2p[lane];
  float ox = fmaxf((ax + bx2) + (cx + dx) + bb.x, 0.f);
  float oy = fmaxf((ay + by2) + (cy + dy) + bb.y, 0.f);

  half2v oh;
  oh[0] = (_Float16)ox;
  oh[1] = (_Float16)oy;
  *(half2v*)&Yh[(size_t)node * D + lane * 2] = oh;
  if (Yf) {
    float2 o; o.x = ox; o.y = oy;
    *(float2*)&Yf[(size_t)node * D + lane * 2] = o;
  }
}

// ---------------- MLP head: MFMA GEMM (128->48 cols, 40 valid) + fused softmax ----
// A: fp16 rows (exact hi/lo split in-kernel). B direct from global (L2-hot).

__global__ __launch_bounds__(256) void k_head(const _Float16* __restrict__ M,
                                              const short* __restrict__ Whi,
                                              const short* __restrict__ Wlo,
                                              const float* __restrict__ b,
                                              float* __restrict__ logits,
                                              float* __restrict__ probs, int n) {
  int tid = threadIdx.x;
  int wave = tid >> 6, lane = tid & 63;
  int q = lane >> 4, r = lane & 15;

  long rowbase = (long)blockIdx.x * 128 + wave * 32;
  long row0 = rowbase + r;
  long row1 = rowbase + 16 + r;
  long rc0 = row0 < n ? row0 : (n - 1);
  long rc1 = row1 < n ? row1 : (n - 1);

  floatx4 acc[2][3];
#pragma unroll
  for (int rt = 0; rt < 2; rt++)
#pragma unroll
    for (int ct = 0; ct < 3; ct++) acc[rt][ct] = (floatx4){0.f, 0.f, 0.f, 0.f};

#pragma unroll
  for (int ks = 0; ks < 4; ks++) {
    half8 a0 = *(const half8*)(M + rc0 * D + ks * 32 + q * 8);
    half8 a1 = *(const half8*)(M + rc1 * D + ks * 32 + q * 8);
    short8 ahi0, alo0, ahi1, alo1;
#pragma unroll
    for (int j = 0; j < 8; j++) {
      float v = (float)a0[j];
      short hi = f2bf(v);
      ahi0[j] = hi; alo0[j] = f2bf(v - bf2f(hi));
      v = (float)a1[j];
      hi = f2bf(v);
      ahi1[j] = hi; alo1[j] = f2bf(v - bf2f(hi));
    }
#pragma unroll
    for (int ct = 0; ct < 3; ct++) {
      int c = ct * 16 + r;
      short8 bh = *(const short8*)&Whi[c * D + ks * 32 + q * 8];
      short8 bl = *(const short8*)&Wlo[c * D + ks * 32 + q * 8];
      acc[0][ct] = __builtin_amdgcn_mfma_f32_16x16x32_bf16(ahi0, bh, acc[0][ct], 0, 0, 0);
      acc[0][ct] = __builtin_amdgcn_mfma_f32_16x16x32_bf16(alo0, bh, acc[0][ct], 0, 0, 0);
      acc[0][ct] = __builtin_amdgcn_mfma_f32_16x16x32_bf16(ahi0, bl, acc[0][ct], 0, 0, 0);
      acc[1][ct] = __builtin_amdgcn_mfma_f32_16x16x32_bf16(ahi1, bh, acc[1][ct], 0, 0, 0);
      acc[1][ct] = __builtin_amdgcn_mfma_f32_16x16x32_bf16(alo1, bh, acc[1][ct], 0, 0, 0);
      acc[1][ct] = __builtin_amdgcn_mfma_f32_16x16x32_bf16(ahi1, bl, acc[1][ct], 0, 0, 0);
    }
  }

  float bb0 = b[r];
  float bb1 = b[16 + r];
  float bb2 = (r < 8) ? b[32 + r] : 0.f;

#pragma unroll
  for (int rt = 0; rt < 2; rt++) {
#pragma unroll
    for (int i = 0; i < 4; i++) {
      long row = rowbase + rt * 16 + q * 4 + i;
      float v0 = acc[rt][0][i] + bb0;
      float v1 = acc[rt][1][i] + bb1;
      float v2 = (r < 8) ? (acc[rt][2][i] + bb2) : -INFINITY;
      float mx = fmaxf(fmaxf(v0, v1), v2);
      mx = fmaxf(mx, __shfl_xor(mx, 1));
      mx = fmaxf(mx, __shfl_xor(mx, 2));
      mx = fmaxf(mx, __shfl_xor(mx, 4));
      mx = fmaxf(mx, __shfl_xor(mx, 8));
      float e0 = expf(v0 - mx);
      float e1 = expf(v1 - mx);
      float e2 = (r < 8) ? expf(v2 - mx) : 0.f;
      float sm = e0 + e1 + e2;
      sm += __shfl_xor(sm, 1);
      sm += __shfl_xor(sm, 2);
      sm += __shfl_xor(sm, 4);
      sm += __shfl_xor(sm, 8);
      float inv = 1.f / sm;
      if (row < n) {
        float* lp = logits + row * 40;
        float* pp = probs + row * 40;
        lp[r] = v0;      pp[r] = e0 * inv;
        lp[16 + r] = v1; pp[16 + r] = e1 * inv;
        if (r < 8) { lp[32 + r] = v2; pp[32 + r] = e2 * inv; }
      }
    }
  }
}

// ---------------- launcher ----------------

extern "C" void kernel_launch(void* const* d_in, const int* in_sizes, int n_in,
                              void* d_out, int out_size, void* d_ws, size_t ws_size,
                              hipStream_t stream) {
  const float* x   = (const float*)d_in[0];
  const int*   ei  = (const int*)d_in[1];
  const float* W1  = (const float*)d_in[2];
  const float* b1  = (const float*)d_in[3];
  const float* W2  = (const float*)d_in[4];
  const float* b2  = (const float*)d_in[5];
  const float* W3  = (const float*)d_in[6];
  const float* b3  = (const float*)d_in[7];
  const float* Wm1 = (const float*)d_in[8];
  const float* bm1 = (const float*)d_in[9];
  const float* Wm2 = (const float*)d_in[10];
  const float* bm2 = (const float*)d_in[11];

  int N = in_sizes[0] / D;
  int E = in_sizes[1] / 2;
  const int* srcp = ei;
  const int* dstp = ei + E;

  char* w = (char*)d_ws;
  auto alloc = [&](size_t bytes) -> char* {
    char* p = w;
    w += (bytes + 255) & ~(size_t)255;
    return p;
  };
  int*   counts = (int*)alloc((size_t)N * 4);
  int*   rowptr = (int*)alloc((size_t)N * 4);
  int*   cursor = (int*)alloc((size_t)N * 4);
  float* dis    = (float*)alloc((size_t)N * 4);
  int*   bsum   = (int*)alloc(1024);
  short* wsplit = (short*)alloc(4 * 32768 * 2);   // 4 weights x (hi+lo 16384 shorts)
  short* w2hi   = (short*)alloc(6144 * 2);
  short* w2lo   = (short*)alloc(6144 * 2);
  int2*  cpack  = (int2*)alloc((size_t)E * 8);
  _Float16* tmp_h  = (_Float16*)alloc((size_t)N * D * 2);
  _Float16* hbuf_h = (_Float16*)alloc((size_t)N * D * 2);

  float* logits = (float*)d_out;
  float* probs  = logits + (size_t)N * 40;
  float* emb    = probs + (size_t)N * 40;

  // weight pre-split
  k_prep<<<(65536 + 6144 + 255) / 256, 256, 0, stream>>>(W1, W2, W3, Wm1, Wm2,
                                                         wsplit, w2hi, w2lo);
  // CSR build (octant-partitioned hist/fill: 8 dst-octants x 128 chunks)
  k_zero<<<(N + 255) / 256, 256, 0, stream>>>(counts, N);
  k_hist<<<1024, 256, 0, stream>>>(dstp, counts, E, N);
  int nb = (N + 1023) / 1024;
  k_scan1<<<nb, 256, 0, stream>>>(counts, rowptr, bsum, N);
  k_scan2<<<1, 256, 0, stream>>>(bsum, nb);
  k_finish<<<(N + 255) / 256, 256, 0, stream>>>(rowptr, cursor, dis, counts, bsum, N);
  k_fill<<<1024, 256, 0, stream>>>(srcp, dstp, cursor, dis, cpack, E, N);

  int gblocks = (N + 127) / 128;
  int ablocks = (N + 3) / 4;
  const short* Whi1 = wsplit;
  const short* Wlo1 = wsplit + 16384;
  const short* Whi2 = wsplit + 32768;
  const short* Wlo2 = wsplit + 32768 + 16384;
  const short* Whi3 = wsplit + 2 * 32768;
  const short* Wlo3 = wsplit + 2 * 32768 + 16384;
  const short* Whm1 = wsplit + 3 * 32768;
  const short* Wlm1 = wsplit + 3 * 32768 + 16384;

  // layer 1 (fp32 A)
  k_gemm<<<gblocks, 256, 0, stream>>>(x, nullptr, Whi1, Wlo1, nullptr,
                                      tmp_h, N, 0, 0);
  k_agg<<<ablocks, 256, 0, stream>>>(tmp_h, rowptr, counts, cpack, dis, b1,
                                     hbuf_h, nullptr, N);
  // layer 2 (fp16 A)
  k_gemm<<<gblocks, 256, 0, stream>>>(nullptr, hbuf_h, Whi2, Wlo2, nullptr,
                                      tmp_h, N, 0, 2);
  k_agg<<<ablocks, 256, 0, stream>>>(tmp_h, rowptr, counts, cpack, dis, b2,
                                     hbuf_h, nullptr, N);
  // layer 3 -> emb (fp16 + fp32)
  k_gemm<<<gblocks, 256, 0, stream>>>(nullptr, hbuf_h, Whi3, Wlo3, nullptr,
                                      tmp_h, N, 0, 2);
  k_agg<<<ablocks, 256, 0, stream>>>(tmp_h, rowptr, counts, cpack, dis, b3,
                                     hbuf_h, emb, N);
  // MLP hidden (fp16 A, ELU, fp16 out)
  k_gemm<<<gblocks, 256, 0, stream>>>(nullptr, hbuf_h, Whm1, Wlm1, bm1,
                                      tmp_h, N, 1, 2);
  // head (fp16 A)
  k_head<<<gblocks, 256, 0, stream>>>(tmp_h, w2hi, w2lo, bm2,
                                      logits, probs, N);
}

// Round 2
// 596.670 us; speedup vs baseline: 1.1400x; 1.1400x over previous
//
#include <hip/hip_runtime.h>
#include <math.h>

#define D 128
#define BINW 256       // nodes per bin (d_local fits in 8 bits)
#define MAXBIN 400     // supports N <= 102400 (harness N = 100000 -> 391 bins)
#define ACHUNK 4096    // edges per passA block
#define BCAP 6144      // passB2 LDS capacity: Binomial(E,256/N) mean 4096, sd 64 -> +32 sd

typedef __attribute__((ext_vector_type(8))) short short8;
typedef __attribute__((ext_vector_type(4))) float floatx4;
typedef __attribute__((ext_vector_type(2))) _Float16 half2v;
typedef __attribute__((ext_vector_type(8))) _Float16 half8;

// ---------------- graph preprocessing ----------------
// CSR build via two-pass counting sort. Round-1 lesson: scattered 8B stores
// cost a full 64B line each (WRITE_SIZE == E*64B) and L2 write-combining
// cannot be provoked (dirty lines evicted before reuse). So every global
// write here is coalesced or a sequential run: passA sorts edges by 256-node
// bin in LDS and emits runs; passB2 sorts each bin into final node order in
// LDS and emits one sequential burst per bin.

__global__ __launch_bounds__(256) void k_zero(int* __restrict__ p, int n) {
  int i = blockIdx.x * 256 + threadIdx.x;
  if (i < n) p[i] = 0;
}

// per-block LDS histogram of dst>>8, flushed once to global
__global__ __launch_bounds__(256) void k_binhist(const int* __restrict__ dst,
                                                 int* __restrict__ gbinc,
                                                 int E, int nbin) {
  __shared__ int h[MAXBIN];
  for (int i = threadIdx.x; i < nbin; i += 256) h[i] = 0;
  __syncthreads();
  int stride = gridDim.x * 256;
  for (int e = blockIdx.x * 256 + (int)threadIdx.x; e < E; e += stride)
    atomicAdd(&h[dst[e] >> 8], 1);
  __syncthreads();
  for (int i = threadIdx.x; i < nbin; i += 256)
    if (h[i]) atomicAdd(&gbinc[i], h[i]);
}

// exclusive scan of bin counts -> binoff[0..nbin]; gbincur = binoff copy
__global__ __launch_bounds__(256) void k_binscan(const int* __restrict__ gbinc,
                                                 int* __restrict__ binoff,
                                                 int* __restrict__ gbincur, int nbin) {
  __shared__ int hv[512];
  __shared__ int sd[256];
  int tid = threadIdx.x;
  for (int i = tid; i < 512; i += 256) hv[i] = (i < nbin) ? gbinc[i] : 0;
  __syncthreads();
  int a = hv[2 * tid], b = hv[2 * tid + 1];
  int s = a + b;
  sd[tid] = s;
  __syncthreads();
  for (int off = 1; off < 256; off <<= 1) {
    int t = (tid >= off) ? sd[tid - off] : 0;
    __syncthreads();
    sd[tid] += t;
    __syncthreads();
  }
  int excl = sd[tid] - s;
  if (2 * tid < nbin)     { binoff[2 * tid] = excl;         gbincur[2 * tid] = excl; }
  if (2 * tid + 1 < nbin) { binoff[2 * tid + 1] = excl + a; gbincur[2 * tid + 1] = excl + a; }
  if (tid == 255) binoff[nbin] = sd[255];
}

// pass A: per-block counting sort of an edge chunk by bin; coalesced run output.
// staging entry: (src << 8) | (dst & 255)  (17 + 8 = 25 bits)
__global__ __launch_bounds__(256) void k_passA(const int* __restrict__ src,
                                               const int* __restrict__ dst,
                                               int* __restrict__ gbincur,
                                               unsigned* __restrict__ staging,
                                               int E, int nbin) {
  __shared__ int hist[MAXBIN];
  __shared__ int lstart[MAXBIN];
  __shared__ int lcur[MAXBIN];
  __shared__ int runbase[MAXBIN];
  __shared__ int sd[256];
  __shared__ unsigned sbuf[ACHUNK];

  int tid = threadIdx.x;
  int e0 = blockIdx.x * ACHUNK;
  int e1 = e0 + ACHUNK < E ? e0 + ACHUNK : E;

  for (int i = tid; i < nbin; i += 256) hist[i] = 0;
  __syncthreads();
  for (int e = e0 + tid; e < e1; e += 256) atomicAdd(&hist[dst[e] >> 8], 1);
  __syncthreads();

  // pair-wise exclusive scan of hist -> lstart
  int a = (2 * tid < nbin) ? hist[2 * tid] : 0;
  int b = (2 * tid + 1 < nbin) ? hist[2 * tid + 1] : 0;
  int s = a + b;
  sd[tid] = s;
  __syncthreads();
  for (int off = 1; off < 256; off <<= 1) {
    int t = (tid >= off) ? sd[tid - off] : 0;
    __syncthreads();
    sd[tid] += t;
    __syncthreads();
  }
  int excl = sd[tid] - s;
  if (2 * tid < nbin) lstart[2 * tid] = excl;
  if (2 * tid + 1 < nbin) lstart[2 * tid + 1] = excl + a;
  __syncthreads();

  // reserve global runs, init cursors
  for (int bx = tid; bx < nbin; bx += 256) {
    int cb = hist[bx];
    runbase[bx] = cb ? atomicAdd(&gbincur[bx], cb) : 0;
    lcur[bx] = lstart[bx];
  }
  __syncthreads();

  // scatter into LDS sorted buffer (chunk re-read is L2-hot)
  for (int e = e0 + tid; e < e1; e += 256) {
    int dd = dst[e];
    int bb = dd >> 8;
    int p = atomicAdd(&lcur[bb], 1);
    sbuf[p] = ((unsigned)src[e] << 8) | (unsigned)(dd & 255);
  }
  __syncthreads();

  // coalesced copy-out: one wave per bin run
  int wv = tid >> 6, ln = tid & 63;
  for (int bx = wv; bx < nbin; bx += 4) {
    int cb = hist[bx], ls = lstart[bx], rb = runbase[bx];
    for (int i = ln; i < cb; i += 64) staging[rb + i] = sbuf[ls + i];
  }
}

// per-node counts from staged bins: LDS atomics + one coalesced write.
__global__ __launch_bounds__(256) void k_nodehist(const unsigned* __restrict__ staging,
                                                  const int* __restrict__ binoff,
                                                  int* __restrict__ counts, int N) {
  __shared__ int cnt[BINW];
  int b = blockIdx.x;
  cnt[threadIdx.x] = 0;
  __syncthreads();
  int s = binoff[b], e = binoff[b + 1];
  for (int i = s + (int)threadIdx.x; i < e; i += 256)
    atomicAdd(&cnt[staging[i] & 255], 1);
  __syncthreads();
  int node = b * BINW + (int)threadIdx.x;
  if (node < N) counts[node] = cnt[threadIdx.x];
}

__global__ __launch_bounds__(256) void k_scan1(const int* __restrict__ in,
                                               int* __restrict__ out,
                                               int* __restrict__ bsum, int n) {
  __shared__ int sd[256];
  int tid = threadIdx.x;
  int base = blockIdx.x * 1024 + tid * 4;
  int v0 = 0, v1 = 0, v2 = 0, v3 = 0;
  if (base + 3 < n) {
    int4 t = *(const int4*)(in + base);
    v0 = t.x; v1 = t.y; v2 = t.z; v3 = t.w;
  } else {
    if (base     < n) v0 = in[base];
    if (base + 1 < n) v1 = in[base + 1];
    if (base + 2 < n) v2 = in[base + 2];
    if (base + 3 < n) v3 = in[base + 3];
  }
  int s = v0 + v1 + v2 + v3;
  sd[tid] = s;
  __syncthreads();
  for (int off = 1; off < 256; off <<= 1) {
    int t = (tid >= off) ? sd[tid - off] : 0;
    __syncthreads();
    sd[tid] += t;
    __syncthreads();
  }
  int incl = sd[tid];
  int excl = incl - s;
  if (tid == 255) bsum[blockIdx.x] = incl;
  int r = excl;
  if (base     < n) out[base]     = r; r += v0;
  if (base + 1 < n) out[base + 1] = r; r += v1;
  if (base + 2 < n) out[base + 2] = r; r += v2;
  if (base + 3 < n) out[base + 3] = r;
}

__global__ __launch_bounds__(256) void k_scan2(int* __restrict__ bsum, int nb) {
  __shared__ int sd[256];
  int tid = threadIdx.x;
  int v = (tid < nb) ? bsum[tid] : 0;
  sd[tid] = v;
  __syncthreads();
  for (int off = 1; off < 256; off <<= 1) {
    int t = (tid >= off) ? sd[tid - off] : 0;
    __syncthreads();
    sd[tid] += t;
    __syncthreads();
  }
  int excl = sd[tid] - v;
  if (tid < nb) bsum[tid] = excl;
}

__global__ __launch_bounds__(256) void k_finish(int* __restrict__ rowptr,
                                                float* __restrict__ dis,
                                                const int* __restrict__ counts,
                                                const int* __restrict__ bsum, int n) {
  int i = blockIdx.x * 256 + threadIdx.x;
  if (i < n) {
    int r = rowptr[i] + bsum[i >> 10];
    rowptr[i] = r;
    dis[i] = rsqrtf((float)(counts[i] + 1));
  }
}

// pass B: sort each bin into final node order in LDS; one sequential burst out.
__global__ __launch_bounds__(256) void k_passB2(const unsigned* __restrict__ staging,
                                                const int* __restrict__ binoff,
                                                const int* __restrict__ rowptr,
                                                const float* __restrict__ dis,
                                                int2* __restrict__ cpack, int N) {
  __shared__ int lcnt[BINW];
  __shared__ int2 obuf[BCAP];
  int b = blockIdx.x, tid = threadIdx.x;
  int node0 = b * BINW;
  int s = binoff[b], e = binoff[b + 1];
  int len = e - s;
  int base = rowptr[node0];
  int node = node0 + tid;
  lcnt[tid] = (node < N) ? (rowptr[node] - base) : 0;
  __syncthreads();
  if (len <= BCAP) {
    for (int i = s + tid; i < e; i += 256) {
      unsigned pk = staging[i];
      int sn = (int)(pk >> 8), dl = (int)(pk & 255u);
      float nw = dis[sn] * dis[node0 + dl];
      int p = atomicAdd(&lcnt[dl], 1);
      obuf[p] = make_int2(sn, __float_as_int(nw));
    }
    __syncthreads();
    for (int i = tid; i < len; i += 256) cpack[base + i] = obuf[i];
  } else {
    // never expected (len > mean+32sd); correct slow path
    for (int i = s + tid; i < e; i += 256) {
      unsigned pk = staging[i];
      int sn = (int)(pk >> 8), dl = (int)(pk & 255u);
      float nw = dis[sn] * dis[node0 + dl];
      int p = atomicAdd(&lcnt[dl], 1);
      cpack[base + p] = make_int2(sn, __float_as_int(nw));
    }
  }
}

// ---------------- weight pre-split (once per call) ----------------

__device__ __forceinline__ short f2bf(float v) {
  unsigned u = __float_as_uint(v);
  unsigned r = (u + 0x7FFFu + ((u >> 16) & 1u)) >> 16;
  return (short)r;
}
__device__ __forceinline__ float bf2f(short s) {
  return __uint_as_float(((unsigned)(unsigned short)s) << 16);
}

__global__ __launch_bounds__(256) void k_prep(const float* __restrict__ W1,
                                              const float* __restrict__ W2,
                                              const float* __restrict__ W3,
                                              const float* __restrict__ Wm1,
                                              const float* __restrict__ Wm2,
                                              short* __restrict__ wsplit,
                                              short* __restrict__ w2hi,
                                              short* __restrict__ w2lo) {
  int idx = blockIdx.x * 256 + threadIdx.x;
  if (idx < 65536) {
    int w = idx >> 14;            // which weight
    int rem = idx & 16383;        // c*128 + k
    int c = rem >> 7, k = rem & 127;
    const float* Ws = (w == 0) ? W1 : (w == 1) ? W2 : (w == 2) ? W3 : Wm1;
    float v = Ws[k * D + c];
    short hi = f2bf(v);
    short lo = f2bf(v - bf2f(hi));
    wsplit[(size_t)w * 32768 + rem] = hi;
    wsplit[(size_t)w * 32768 + 16384 + rem] = lo;
  } else if (idx < 65536 + 6144) {
    int i2 = idx - 65536;         // c*128 + k, c in 0..47
    int c = i2 >> 7, k = i2 & 127;
    float v = (c < 40) ? Wm2[k * 40 + c] : 0.f;
    short hi = f2bf(v);
    short lo = f2bf(v - bf2f(hi));
    w2hi[i2] = hi;
    w2lo[i2] = lo;
  }
}

// ---------------- bf16-split MFMA GEMM: Y = X @ W (+bias, +ELU) ----------------

__device__ __forceinline__ float elu1(float x) {
  return x > 0.f ? x : (expf(x) - 1.f);
}

__global__ __launch_bounds__(256, 2) void k_gemm(const float* __restrict__ Xf,
                                                 const _Float16* __restrict__ Xh,
                                                 const short* __restrict__ Whi,
                                                 const short* __restrict__ Wlo,
                                                 const float* __restrict__ bias,
                                                 _Float16* __restrict__ Yh,
                                                 int n, int act, int amode) {
  __shared__ short wthi[128 * 72];  // [c][kk-half], padded stride 72 (144B, 16B-aligned)
  __shared__ short wtlo[128 * 72];

  int tid = threadIdx.x;
  int wave = tid >> 6, lane = tid & 63;
  int q = lane >> 4, r = lane & 15;

  long rowbase = (long)blockIdx.x * 128 + wave * 32;
  long row0 = rowbase + r;
  long row1 = rowbase + 16 + r;
  long rc0 = row0 < n ? row0 : (n - 1);
  long rc1 = row1 < n ? row1 : (n - 1);

  floatx4 acc[2][8];
#pragma unroll
  for (int rt = 0; rt < 2; rt++)
#pragma unroll
    for (int ct = 0; ct < 8; ct++) acc[rt][ct] = (floatx4){0.f, 0.f, 0.f, 0.f};

  for (int h = 0; h < 2; h++) {
    __syncthreads();
    // stage half-K of pre-split W images into padded LDS
#pragma unroll
    for (int i = 0; i < 4; i++) {
      int cs = i * 256 + tid;           // 1024 chunks of 8 shorts
      int c = cs >> 3, o = (cs & 7) * 8;
      *(short8*)&wthi[c * 72 + o] = *(const short8*)&Whi[c * D + h * 64 + o];
      *(short8*)&wtlo[c * 72 + o] = *(const short8*)&Wlo[c * D + h * 64 + o];
    }
    __syncthreads();

#pragma unroll
    for (int ks2 = 0; ks2 < 2; ks2++) {
      int ksg = h * 2 + ks2;            // global k-step 0..3
      int kk0 = ks2 * 32;
      short8 ahi0, alo0, ahi1, alo1;
      if (amode == 2) {
        half8 a0 = *(const half8*)(Xh + rc0 * D + ksg * 32 + q * 8);
        half8 a1 = *(const half8*)(Xh + rc1 * D + ksg * 32 + q * 8);
#pragma unroll
        for (int j = 0; j < 8; j++) {
          float v = (float)a0[j];
          short hi = f2bf(v);
          ahi0[j] = hi; alo0[j] = f2bf(v - bf2f(hi));
          v = (float)a1[j];
          hi = f2bf(v);
          ahi1[j] = hi; alo1[j] = f2bf(v - bf2f(hi));
        }
      } else {
        const floatx4* x0 = (const floatx4*)(Xf + rc0 * D);
        const floatx4* x1 = (const floatx4*)(Xf + rc1 * D);
        int xi = ksg * 8 + q * 2;
        floatx4 a0 = x0[xi], a0b = x0[xi + 1];
        floatx4 a1 = x1[xi], a1b = x1[xi + 1];
#pragma unroll
        for (int j = 0; j < 4; j++) {
          float v = a0[j];  short hi = f2bf(v);
          ahi0[j] = hi; alo0[j] = f2bf(v - bf2f(hi));
          v = a0b[j]; hi = f2bf(v);
          ahi0[4 + j] = hi; alo0[4 + j] = f2bf(v - bf2f(hi));
          v = a1[j];  hi = f2bf(v);
          ahi1[j] = hi; alo1[j] = f2bf(v - bf2f(hi));
          v = a1b[j]; hi = f2bf(v);
          ahi1[4 + j] = hi; alo1[4 + j] = f2bf(v - bf2f(hi));
        }
      }
#pragma unroll
      for (int ct = 0; ct < 8; ct++) {
        int c = ct * 16 + r;
        short8 bh = *(const short8*)&wthi[c * 72 + kk0 + q * 8];
        short8 bl = *(const short8*)&wtlo[c * 72 + kk0 + q * 8];
        acc[0][ct] = __builtin_amdgcn_mfma_f32_16x16x32_bf16(ahi0, bh, acc[0][ct], 0, 0, 0);
        acc[0][ct] = __builtin_amdgcn_mfma_f32_16x16x32_bf16(alo0, bh, acc[0][ct], 0, 0, 0);
        acc[0][ct] = __builtin_amdgcn_mfma_f32_16x16x32_bf16(ahi0, bl, acc[0][ct], 0, 0, 0);
        acc[1][ct] = __builtin_amdgcn_mfma_f32_16x16x32_bf16(ahi1, bh, acc[1][ct], 0, 0, 0);
        acc[1][ct] = __builtin_amdgcn_mfma_f32_16x16x32_bf16(alo1, bh, acc[1][ct], 0, 0, 0);
        acc[1][ct] = __builtin_amdgcn_mfma_f32_16x16x32_bf16(ahi1, bl, acc[1][ct], 0, 0, 0);
      }
    }
  }

  // epilogue: C/D layout col = lane&15, row = q*4 + reg; fp16 out
#pragma unroll
  for (int rt = 0; rt < 2; rt++) {
#pragma unroll
    for (int i = 0; i < 4; i++) {
      long row = rowbase + rt * 16 + q * 4 + i;
      if (row < n) {
#pragma unroll
        for (int ct = 0; ct < 8; ct++) {
          int col = ct * 16 + r;
          float v = acc[rt][ct][i];
          if (bias) v += bias[col];
          if (act == 1) v = elu1(v);
          Yh[row * D + col] = (_Float16)v;
        }
      }
    }
  }
}

// ---------------- aggregation ----------------

__global__ __launch_bounds__(256) void k_agg(const _Float16* __restrict__ T,
                                             const int* __restrict__ rowptr,
                                             const int* __restrict__ counts,
                                             const int2* __restrict__ cpack,
                                             const float* __restrict__ dis,
                                             const float* __restrict__ bias,
                                             _Float16* __restrict__ Yh,
                                             float* __restrict__ Yf, int n) {
  int node = blockIdx.x * 4 + (threadIdx.x >> 6);
  if (node >= n) return;
  int lane = threadIdx.x & 63;
  const half2v* T2 = (const half2v*)T;

  int s = rowptr[node];
  int e = s + counts[node];
  float dv = dis[node];
  half2v t = T2[(size_t)node * 64 + lane];
  float ax = (float)t[0] * (dv * dv), ay = (float)t[1] * (dv * dv);
  float bx2 = 0.f, by2 = 0.f, cx = 0.f, cy = 0.f, dx = 0.f, dy = 0.f;

  int j = s;
  for (; j + 7 < e; j += 8) {
    int2 m0 = cpack[j],     m1 = cpack[j + 1], m2 = cpack[j + 2], m3 = cpack[j + 3];
    int2 m4 = cpack[j + 4], m5 = cpack[j + 5], m6 = cpack[j + 6], m7 = cpack[j + 7];
    half2v v0 = T2[(size_t)m0.x * 64 + lane];
    half2v v1 = T2[(size_t)m1.x * 64 + lane];
    half2v v2 = T2[(size_t)m2.x * 64 + lane];
    half2v v3 = T2[(size_t)m3.x * 64 + lane];
    half2v v4 = T2[(size_t)m4.x * 64 + lane];
    half2v v5 = T2[(size_t)m5.x * 64 + lane];
    half2v v6 = T2[(size_t)m6.x * 64 + lane];
    half2v v7 = T2[(size_t)m7.x * 64 + lane];
    float n0 = __int_as_float(m0.y), n1 = __int_as_float(m1.y);
    float n2 = __int_as_float(m2.y), n3 = __int_as_float(m3.y);
    float n4 = __int_as_float(m4.y), n5 = __int_as_float(m5.y);
    float n6 = __int_as_float(m6.y), n7 = __int_as_float(m7.y);
    ax  += (float)v0[0] * n0; ay  += (float)v0[1] * n0;
    bx2 += (float)v1[0] * n1; by2 += (float)v1[1] * n1;
    cx  += (float)v2[0] * n2; cy  += (float)v2[1] * n2;
    dx  += (float)v3[0] * n3; dy  += (float)v3[1] * n3;
    ax  += (float)v4[0] * n4; ay  += (float)v4[1] * n4;
    bx2 += (float)v5[0] * n5; by2 += (float)v5[1] * n5;
    cx  += (float)v6[0] * n6; cy  += (float)v6[1] * n6;
    dx  += (float)v7[0] * n7; dy  += (float)v7[1] * n7;
  }
  for (; j + 3 < e; j += 4) {
    int2 m0 = cpack[j], m1 = cpack[j + 1], m2 = cpack[j + 2], m3 = cpack[j + 3];
    half2v v0 = T2[(size_t)m0.x * 64 + lane];
    half2v v1 = T2[(size_t)m1.x * 64 + lane];
    half2v v2 = T2[(size_t)m2.x * 64 + lane];
    half2v v3 = T2[(size_t)m3.x * 64 + lane];
    float n0 = __int_as_float(m0.y), n1 = __int_as_float(m1.y);
    float n2 = __int_as_float(m2.y), n3 = __int_as_float(m3.y);
    ax  += (float)v0[0] * n0; ay  += (float)v0[1] * n0;
    bx2 += (float)v1[0] * n1; by2 += (float)v1[1] * n1;
    cx  += (float)v2[0] * n2; cy  += (float)v2[1] * n2;
    dx  += (float)v3[0] * n3; dy  += (float)v3[1] * n3;
  }
  for (; j < e; ++j) {
    int2 m0 = cpack[j];
    half2v v0 = T2[(size_t)m0.x * 64 + lane];
    float n0 = __int_as_float(m0.y);
    ax += (float)v0[0] * n0; ay += (float)v0[1] * n0;
  }

  const float2* b2p = (const float2*)bias;
  float2 bb = b2p[lane];
  float ox = fmaxf((ax + bx2) + (cx + dx) + bb.x, 0.f);
  float oy = fmaxf((ay + by2) + (cy + dy) + bb.y, 0.f);

  half2v oh;
  oh[0] = (_Float16)ox;
  oh[1] = (_Float16)oy;
  *(half2v*)&Yh[(size_t)node * D + lane * 2] = oh;
  if (Yf) {
    float2 o; o.x = ox; o.y = oy;
    *(float2*)&Yf[(size_t)node * D + lane * 2] = o;
  }
}

// ---------------- MLP head ----------------

__global__ __launch_bounds__(256) void k_head(const _Float16* __restrict__ M,
                                              const short* __restrict__ Whi,
                                              const short* __restrict__ Wlo,
                                              const float* __restrict__ b,
                                              float* __restrict__ logits,
                                              float* __restrict__ probs, int n) {
  int tid = threadIdx.x;
  int wave = tid >> 6, lane = tid & 63;
  int q = lane >> 4, r = lane & 15;

  long rowbase = (long)blockIdx.x * 128 + wave * 32;
  long row0 = rowbase + r;
  long row1 = rowbase + 16 + r;
  long rc0 = row0 < n ? row0 : (n - 1);
  long rc1 = row1 < n ? row1 : (n - 1);

  floatx4 acc[2][3];
#pragma unroll
  for (int rt = 0; rt < 2; rt++)
#pragma unroll
    for (int ct = 0; ct < 3; ct++) acc[rt][ct] = (floatx4){0.f, 0.f, 0.f, 0.f};

#pragma unroll
  for (int ks = 0; ks < 4; ks++) {
    half8 a0 = *(const half8*)(M + rc0 * D + ks * 32 + q * 8);
    half8 a1 = *(const half8*)(M + rc1 * D + ks * 32 + q * 8);
    short8 ahi0, alo0, ahi1, alo1;
#pragma unroll
    for (int j = 0; j < 8; j++) {
      float v = (float)a0[j];
      short hi = f2bf(v);
      ahi0[j] = hi; alo0[j] = f2bf(v - bf2f(hi));
      v = (float)a1[j];
      hi = f2bf(v);
      ahi1[j] = hi; alo1[j] = f2bf(v - bf2f(hi));
    }
#pragma unroll
    for (int ct = 0; ct < 3; ct++) {
      int c = ct * 16 + r;
      short8 bh = *(const short8*)&Whi[c * D + ks * 32 + q * 8];
      short8 bl = *(const short8*)&Wlo[c * D + ks * 32 + q * 8];
      acc[0][ct] = __builtin_amdgcn_mfma_f32_16x16x32_bf16(ahi0, bh, acc[0][ct], 0, 0, 0);
      acc[0][ct] = __builtin_amdgcn_mfma_f32_16x16x32_bf16(alo0, bh, acc[0][ct], 0, 0, 0);
      acc[0][ct] = __builtin_amdgcn_mfma_f32_16x16x32_bf16(ahi0, bl, acc[0][ct], 0, 0, 0);
      acc[1][ct] = __builtin_amdgcn_mfma_f32_16x16x32_bf16(ahi1, bh, acc[1][ct], 0, 0, 0);
      acc[1][ct] = __builtin_amdgcn_mfma_f32_16x16x32_bf16(alo1, bh, acc[1][ct], 0, 0, 0);
      acc[1][ct] = __builtin_amdgcn_mfma_f32_16x16x32_bf16(ahi1, bl, acc[1][ct], 0, 0, 0);
    }
  }

  float bb0 = b[r];
  float bb1 = b[16 + r];
  float bb2 = (r < 8) ? b[32 + r] : 0.f;

#pragma unroll
  for (int rt = 0; rt < 2; rt++) {
#pragma unroll
    for (int i = 0; i < 4; i++) {
      long row = rowbase + rt * 16 + q * 4 + i;
      float v0 = acc[rt][0][i] + bb0;
      float v1 = acc[rt][1][i] + bb1;
      float v2 = (r < 8) ? (acc[rt][2][i] + bb2) : -INFINITY;
      float mx = fmaxf(fmaxf(v0, v1), v2);
      mx = fmaxf(mx, __shfl_xor(mx, 1));
      mx = fmaxf(mx, __shfl_xor(mx, 2));
      mx = fmaxf(mx, __shfl_xor(mx, 4));
      mx = fmaxf(mx, __shfl_xor(mx, 8));
      float e0 = expf(v0 - mx);
      float e1 = expf(v1 - mx);
      float e2 = (r < 8) ? expf(v2 - mx) : 0.f;
      float sm = e0 + e1 + e2;
      sm += __shfl_xor(sm, 1);
      sm += __shfl_xor(sm, 2);
      sm += __shfl_xor(sm, 4);
      sm += __shfl_xor(sm, 8);
      float inv = 1.f / sm;
      if (row < n) {
        float* lp = logits + row * 40;
        float* pp = probs + row * 40;
        lp[r] = v0;      pp[r] = e0 * inv;
        lp[16 + r] = v1; pp[16 + r] = e1 * inv;
        if (r < 8) { lp[32 + r] = v2; pp[32 + r] = e2 * inv; }
      }
    }
  }
}

// ---------------- launcher ----------------

extern "C" void kernel_launch(void* const* d_in, const int* in_sizes, int n_in,
                              void* d_out, int out_size, void* d_ws, size_t ws_size,
                              hipStream_t stream) {
  const float* x   = (const float*)d_in[0];
  const int*   ei  = (const int*)d_in[1];
  const float* W1  = (const float*)d_in[2];
  const float* b1  = (const float*)d_in[3];
  const float* W2  = (const float*)d_in[4];
  const float* b2  = (const float*)d_in[5];
  const float* W3  = (const float*)d_in[6];
  const float* b3  = (const float*)d_in[7];
  const float* Wm1 = (const float*)d_in[8];
  const float* bm1 = (const float*)d_in[9];
  const float* Wm2 = (const float*)d_in[10];
  const float* bm2 = (const float*)d_in[11];

  int N = in_sizes[0] / D;
  int E = in_sizes[1] / 2;
  const int* srcp = ei;
  const int* dstp = ei + E;
  int NBIN = (N + BINW - 1) / BINW;

  char* w = (char*)d_ws;
  auto alloc = [&](size_t bytes) -> char* {
    char* p = w;
    w += (bytes + 255) & ~(size_t)255;
    return p;
  };
  int*   counts = (int*)alloc((size_t)N * 4);
  int*   rowptr = (int*)alloc((size_t)N * 4);
  float* dis    = (float*)alloc((size_t)N * 4);
  int*   bsum   = (int*)alloc(1024);
  int*   gbinc  = (int*)alloc(MAXBIN * 4);
  int*   binoff = (int*)alloc((MAXBIN + 1) * 4);
  int*   gbincur= (int*)alloc(MAXBIN * 4);
  short* wsplit = (short*)alloc(4 * 32768 * 2);
  short* w2hi   = (short*)alloc(6144 * 2);
  short* w2lo   = (short*)alloc(6144 * 2);
  int2*  cpack  = (int2*)alloc((size_t)E * 8);
  _Float16* tmp_h  = (_Float16*)alloc((size_t)N * D * 2);
  _Float16* hbuf_h = (_Float16*)alloc((size_t)N * D * 2);
  // staging (E x 4B) aliases tmp_h: dead until the first GEMM writes it,
  // and passB2 (last reader) precedes that in stream order.
  unsigned* staging = (unsigned*)tmp_h;

  float* logits = (float*)d_out;
  float* probs  = logits + (size_t)N * 40;
  float* emb    = probs + (size_t)N * 40;

  // weight pre-split
  k_prep<<<(65536 + 6144 + 255) / 256, 256, 0, stream>>>(W1, W2, W3, Wm1, Wm2,
                                                         wsplit, w2hi, w2lo);
  // CSR build: bin-hist -> scan -> bin-sort -> node-hist -> scan -> bin-sort2
  k_zero<<<(NBIN + 255) / 256, 256, 0, stream>>>(gbinc, NBIN);
  k_binhist<<<256, 256, 0, stream>>>(dstp, gbinc, E, NBIN);
  k_binscan<<<1, 256, 0, stream>>>(gbinc, binoff, gbincur, NBIN);
  k_passA<<<(E + ACHUNK - 1) / ACHUNK, 256, 0, stream>>>(srcp, dstp, gbincur,
                                                         staging, E, NBIN);
  k_nodehist<<<NBIN, 256, 0, stream>>>(staging, binoff, counts, N);
  int nb = (N + 1023) / 1024;
  k_scan1<<<nb, 256, 0, stream>>>(counts, rowptr, bsum, N);
  k_scan2<<<1, 256, 0, stream>>>(bsum, nb);
  k_finish<<<(N + 255) / 256, 256, 0, stream>>>(rowptr, dis, counts, bsum, N);
  k_passB2<<<NBIN, 256, 0, stream>>>(staging, binoff, rowptr, dis, cpack, N);

  int gblocks = (N + 127) / 128;
  int ablocks = (N + 3) / 4;
  const short* Whi1 = wsplit;
  const short* Wlo1 = wsplit + 16384;
  const short* Whi2 = wsplit + 32768;
  const short* Wlo2 = wsplit + 32768 + 16384;
  const short* Whi3 = wsplit + 2 * 32768;
  const short* Wlo3 = wsplit + 2 * 32768 + 16384;
  const short* Whm1 = wsplit + 3 * 32768;
  const short* Wlm1 = wsplit + 3 * 32768 + 16384;

  // layer 1 (fp32 A)
  k_gemm<<<gblocks, 256, 0, stream>>>(x, nullptr, Whi1, Wlo1, nullptr,
                                      tmp_h, N, 0, 0);
  k_agg<<<ablocks, 256, 0, stream>>>(tmp_h, rowptr, counts, cpack, dis, b1,
                                     hbuf_h, nullptr, N);
  // layer 2 (fp16 A)
  k_gemm<<<gblocks, 256, 0, stream>>>(nullptr, hbuf_h, Whi2, Wlo2, nullptr,
                                      tmp_h, N, 0, 2);
  k_agg<<<ablocks, 256, 0, stream>>>(tmp_h, rowptr, counts, cpack, dis, b2,
                                     hbuf_h, nullptr, N);
  // layer 3 -> emb (fp16 + fp32)
  k_gemm<<<gblocks, 256, 0, stream>>>(nullptr, hbuf_h, Whi3, Wlo3, nullptr,
                                      tmp_h, N, 0, 2);
  k_agg<<<ablocks, 256, 0, stream>>>(tmp_h, rowptr, counts, cpack, dis, b3,
                                     hbuf_h, emb, N);
  // MLP hidden (fp16 A, ELU, fp16 out)
  k_gemm<<<gblocks, 256, 0, stream>>>(nullptr, hbuf_h, Whm1, Wlm1, bm1,
                                      tmp_h, N, 1, 2);
  // head (fp16 A)
  k_head<<<gblocks, 256, 0, stream>>>(tmp_h, w2hi, w2lo, bm2,
                                      logits, probs, N);
}

// Round 3
// 582.562 us; speedup vs baseline: 1.1676x; 1.0242x over previous
//
#include <hip/hip_runtime.h>
#include <math.h>

#define D 128
#define BINW 256       // nodes per bin (d_local fits in 8 bits)
#define MAXBIN 400     // supports N <= 102400 (harness N = 100000 -> 391 bins)
#define ACHUNK 4096    // edges per passA block
#define BCAP 6144      // passB2 LDS capacity: Binomial(E,256/N) mean 4096, sd 64 -> +32 sd

typedef __attribute__((ext_vector_type(8))) short short8;
typedef __attribute__((ext_vector_type(4))) float floatx4;
typedef __attribute__((ext_vector_type(8))) _Float16 half8;

// ---------------- graph preprocessing ----------------
// CSR build via two-pass counting sort. Round-1 lesson: scattered 8B stores
// cost a full 64B line each (WRITE_SIZE == E*64B) and L2 write-combining
// cannot be provoked (dirty lines evicted before reuse). So every global
// write here is coalesced or a sequential run: passA sorts edges by 256-node
// bin in LDS and emits runs; passB2 sorts each bin into final node order in
// LDS and emits one sequential burst per bin. (R2: validated, 658->597 us.)

__global__ __launch_bounds__(256) void k_zero(int* __restrict__ p, int n) {
  int i = blockIdx.x * 256 + threadIdx.x;
  if (i < n) p[i] = 0;
}

// per-block LDS histogram of dst>>8, flushed once to global
__global__ __launch_bounds__(256) void k_binhist(const int* __restrict__ dst,
                                                 int* __restrict__ gbinc,
                                                 int E, int nbin) {
  __shared__ int h[MAXBIN];
  for (int i = threadIdx.x; i < nbin; i += 256) h[i] = 0;
  __syncthreads();
  int stride = gridDim.x * 256;
  for (int e = blockIdx.x * 256 + (int)threadIdx.x; e < E; e += stride)
    atomicAdd(&h[dst[e] >> 8], 1);
  __syncthreads();
  for (int i = threadIdx.x; i < nbin; i += 256)
    if (h[i]) atomicAdd(&gbinc[i], h[i]);
}

// exclusive scan of bin counts -> binoff[0..nbin]; gbincur = binoff copy
__global__ __launch_bounds__(256) void k_binscan(const int* __restrict__ gbinc,
                                                 int* __restrict__ binoff,
                                                 int* __restrict__ gbincur, int nbin) {
  __shared__ int hv[512];
  __shared__ int sd[256];
  int tid = threadIdx.x;
  for (int i = tid; i < 512; i += 256) hv[i] = (i < nbin) ? gbinc[i] : 0;
  __syncthreads();
  int a = hv[2 * tid], b = hv[2 * tid + 1];
  int s = a + b;
  sd[tid] = s;
  __syncthreads();
  for (int off = 1; off < 256; off <<= 1) {
    int t = (tid >= off) ? sd[tid - off] : 0;
    __syncthreads();
    sd[tid] += t;
    __syncthreads();
  }
  int excl = sd[tid] - s;
  if (2 * tid < nbin)     { binoff[2 * tid] = excl;         gbincur[2 * tid] = excl; }
  if (2 * tid + 1 < nbin) { binoff[2 * tid + 1] = excl + a; gbincur[2 * tid + 1] = excl + a; }
  if (tid == 255) binoff[nbin] = sd[255];
}

// pass A: per-block counting sort of an edge chunk by bin; coalesced run output.
// staging entry: (src << 8) | (dst & 255)  (17 + 8 = 25 bits)
__global__ __launch_bounds__(256) void k_passA(const int* __restrict__ src,
                                               const int* __restrict__ dst,
                                               int* __restrict__ gbincur,
                                               unsigned* __restrict__ staging,
                                               int E, int nbin) {
  __shared__ int hist[MAXBIN];
  __shared__ int lstart[MAXBIN];
  __shared__ int lcur[MAXBIN];
  __shared__ int runbase[MAXBIN];
  __shared__ int sd[256];
  __shared__ unsigned sbuf[ACHUNK];

  int tid = threadIdx.x;
  int e0 = blockIdx.x * ACHUNK;
  int e1 = e0 + ACHUNK < E ? e0 + ACHUNK : E;

  for (int i = tid; i < nbin; i += 256) hist[i] = 0;
  __syncthreads();
  for (int e = e0 + tid; e < e1; e += 256) atomicAdd(&hist[dst[e] >> 8], 1);
  __syncthreads();

  // pair-wise exclusive scan of hist -> lstart
  int a = (2 * tid < nbin) ? hist[2 * tid] : 0;
  int b = (2 * tid + 1 < nbin) ? hist[2 * tid + 1] : 0;
  int s = a + b;
  sd[tid] = s;
  __syncthreads();
  for (int off = 1; off < 256; off <<= 1) {
    int t = (tid >= off) ? sd[tid - off] : 0;
    __syncthreads();
    sd[tid] += t;
    __syncthreads();
  }
  int excl = sd[tid] - s;
  if (2 * tid < nbin) lstart[2 * tid] = excl;
  if (2 * tid + 1 < nbin) lstart[2 * tid + 1] = excl + a;
  __syncthreads();

  // reserve global runs, init cursors
  for (int bx = tid; bx < nbin; bx += 256) {
    int cb = hist[bx];
    runbase[bx] = cb ? atomicAdd(&gbincur[bx], cb) : 0;
    lcur[bx] = lstart[bx];
  }
  __syncthreads();

  // scatter into LDS sorted buffer (chunk re-read is L2-hot)
  for (int e = e0 + tid; e < e1; e += 256) {
    int dd = dst[e];
    int bb = dd >> 8;
    int p = atomicAdd(&lcur[bb], 1);
    sbuf[p] = ((unsigned)src[e] << 8) | (unsigned)(dd & 255);
  }
  __syncthreads();

  // coalesced copy-out: one wave per bin run
  int wv = tid >> 6, ln = tid & 63;
  for (int bx = wv; bx < nbin; bx += 4) {
    int cb = hist[bx], ls = lstart[bx], rb = runbase[bx];
    for (int i = ln; i < cb; i += 64) staging[rb + i] = sbuf[ls + i];
  }
}

// per-node counts from staged bins: LDS atomics + one coalesced write.
__global__ __launch_bounds__(256) void k_nodehist(const unsigned* __restrict__ staging,
                                                  const int* __restrict__ binoff,
                                                  int* __restrict__ counts, int N) {
  __shared__ int cnt[BINW];
  int b = blockIdx.x;
  cnt[threadIdx.x] = 0;
  __syncthreads();
  int s = binoff[b], e = binoff[b + 1];
  for (int i = s + (int)threadIdx.x; i < e; i += 256)
    atomicAdd(&cnt[staging[i] & 255], 1);
  __syncthreads();
  int node = b * BINW + (int)threadIdx.x;
  if (node < N) counts[node] = cnt[threadIdx.x];
}

__global__ __launch_bounds__(256) void k_scan1(const int* __restrict__ in,
                                               int* __restrict__ out,
                                               int* __restrict__ bsum, int n) {
  __shared__ int sd[256];
  int tid = threadIdx.x;
  int base = blockIdx.x * 1024 + tid * 4;
  int v0 = 0, v1 = 0, v2 = 0, v3 = 0;
  if (base + 3 < n) {
    int4 t = *(const int4*)(in + base);
    v0 = t.x; v1 = t.y; v2 = t.z; v3 = t.w;
  } else {
    if (base     < n) v0 = in[base];
    if (base + 1 < n) v1 = in[base + 1];
    if (base + 2 < n) v2 = in[base + 2];
    if (base + 3 < n) v3 = in[base + 3];
  }
  int s = v0 + v1 + v2 + v3;
  sd[tid] = s;
  __syncthreads();
  for (int off = 1; off < 256; off <<= 1) {
    int t = (tid >= off) ? sd[tid - off] : 0;
    __syncthreads();
    sd[tid] += t;
    __syncthreads();
  }
  int incl = sd[tid];
  int excl = incl - s;
  if (tid == 255) bsum[blockIdx.x] = incl;
  int r = excl;
  if (base     < n) out[base]     = r; r += v0;
  if (base + 1 < n) out[base + 1] = r; r += v1;
  if (base + 2 < n) out[base + 2] = r; r += v2;
  if (base + 3 < n) out[base + 3] = r;
}

__global__ __launch_bounds__(256) void k_scan2(int* __restrict__ bsum, int nb) {
  __shared__ int sd[256];
  int tid = threadIdx.x;
  int v = (tid < nb) ? bsum[tid] : 0;
  sd[tid] = v;
  __syncthreads();
  for (int off = 1; off < 256; off <<= 1) {
    int t = (tid >= off) ? sd[tid - off] : 0;
    __syncthreads();
    sd[tid] += t;
    __syncthreads();
  }
  int excl = sd[tid] - v;
  if (tid < nb) bsum[tid] = excl;
}

__global__ __launch_bounds__(256) void k_finish(int* __restrict__ rowptr,
                                                float* __restrict__ dis,
                                                const int* __restrict__ counts,
                                                const int* __restrict__ bsum, int n) {
  int i = blockIdx.x * 256 + threadIdx.x;
  if (i < n) {
    int r = rowptr[i] + bsum[i >> 10];
    rowptr[i] = r;
    dis[i] = rsqrtf((float)(counts[i] + 1));
  }
}

// pass B: sort each bin into final node order in LDS; one sequential burst out.
__global__ __launch_bounds__(256) void k_passB2(const unsigned* __restrict__ staging,
                                                const int* __restrict__ binoff,
                                                const int* __restrict__ rowptr,
                                                const float* __restrict__ dis,
                                                int2* __restrict__ cpack, int N) {
  __shared__ int lcnt[BINW];
  __shared__ int2 obuf[BCAP];
  int b = blockIdx.x, tid = threadIdx.x;
  int node0 = b * BINW;
  int s = binoff[b], e = binoff[b + 1];
  int len = e - s;
  int base = rowptr[node0];
  int node = node0 + tid;
  lcnt[tid] = (node < N) ? (rowptr[node] - base) : 0;
  __syncthreads();
  if (len <= BCAP) {
    for (int i = s + tid; i < e; i += 256) {
      unsigned pk = staging[i];
      int sn = (int)(pk >> 8), dl = (int)(pk & 255u);
      float nw = dis[sn] * dis[node0 + dl];
      int p = atomicAdd(&lcnt[dl], 1);
      obuf[p] = make_int2(sn, __float_as_int(nw));
    }
    __syncthreads();
    for (int i = tid; i < len; i += 256) cpack[base + i] = obuf[i];
  } else {
    // never expected (len > mean+32sd); correct slow path
    for (int i = s + tid; i < e; i += 256) {
      unsigned pk = staging[i];
      int sn = (int)(pk >> 8), dl = (int)(pk & 255u);
      float nw = dis[sn] * dis[node0 + dl];
      int p = atomicAdd(&lcnt[dl], 1);
      cpack[base + p] = make_int2(sn, __float_as_int(nw));
    }
  }
}

// ---------------- weight pre-split (once per call) ----------------

__device__ __forceinline__ short f2bf(float v) {
  unsigned u = __float_as_uint(v);
  unsigned r = (u + 0x7FFFu + ((u >> 16) & 1u)) >> 16;
  return (short)r;
}
__device__ __forceinline__ float bf2f(short s) {
  return __uint_as_float(((unsigned)(unsigned short)s) << 16);
}

__global__ __launch_bounds__(256) void k_prep(const float* __restrict__ W1,
                                              const float* __restrict__ W2,
                                              const float* __restrict__ W3,
                                              const float* __restrict__ Wm1,
                                              const float* __restrict__ Wm2,
                                              short* __restrict__ wsplit,
                                              short* __restrict__ w2hi,
                                              short* __restrict__ w2lo) {
  int idx = blockIdx.x * 256 + threadIdx.x;
  if (idx < 65536) {
    int w = idx >> 14;            // which weight
    int rem = idx & 16383;        // c*128 + k
    int c = rem >> 7, k = rem & 127;
    const float* Ws = (w == 0) ? W1 : (w == 1) ? W2 : (w == 2) ? W3 : Wm1;
    float v = Ws[k * D + c];
    short hi = f2bf(v);
    short lo = f2bf(v - bf2f(hi));
    wsplit[(size_t)w * 32768 + rem] = hi;
    wsplit[(size_t)w * 32768 + 16384 + rem] = lo;
  } else if (idx < 65536 + 6144) {
    int i2 = idx - 65536;         // c*128 + k, c in 0..47
    int c = i2 >> 7, k = i2 & 127;
    float v = (c < 40) ? Wm2[k * 40 + c] : 0.f;
    short hi = f2bf(v);
    short lo = f2bf(v - bf2f(hi));
    w2hi[i2] = hi;
    w2lo[i2] = lo;
  }
}

// ---------------- bf16-split MFMA GEMM: Y = X @ W (+bias, +ELU) ----------------

__device__ __forceinline__ float elu1(float x) {
  return x > 0.f ? x : (expf(x) - 1.f);
}

__global__ __launch_bounds__(256, 2) void k_gemm(const float* __restrict__ Xf,
                                                 const _Float16* __restrict__ Xh,
                                                 const short* __restrict__ Whi,
                                                 const short* __restrict__ Wlo,
                                                 const float* __restrict__ bias,
                                                 _Float16* __restrict__ Yh,
                                                 int n, int act, int amode) {
  __shared__ short wthi[128 * 72];  // [c][kk-half], padded stride 72 (144B, 16B-aligned)
  __shared__ short wtlo[128 * 72];

  int tid = threadIdx.x;
  int wave = tid >> 6, lane = tid & 63;
  int q = lane >> 4, r = lane & 15;

  long rowbase = (long)blockIdx.x * 128 + wave * 32;
  long row0 = rowbase + r;
  long row1 = rowbase + 16 + r;
  long rc0 = row0 < n ? row0 : (n - 1);
  long rc1 = row1 < n ? row1 : (n - 1);

  floatx4 acc[2][8];
#pragma unroll
  for (int rt = 0; rt < 2; rt++)
#pragma unroll
    for (int ct = 0; ct < 8; ct++) acc[rt][ct] = (floatx4){0.f, 0.f, 0.f, 0.f};

  for (int h = 0; h < 2; h++) {
    __syncthreads();
    // stage half-K of pre-split W images into padded LDS
#pragma unroll
    for (int i = 0; i < 4; i++) {
      int cs = i * 256 + tid;           // 1024 chunks of 8 shorts
      int c = cs >> 3, o = (cs & 7) * 8;
      *(short8*)&wthi[c * 72 + o] = *(const short8*)&Whi[c * D + h * 64 + o];
      *(short8*)&wtlo[c * 72 + o] = *(const short8*)&Wlo[c * D + h * 64 + o];
    }
    __syncthreads();

#pragma unroll
    for (int ks2 = 0; ks2 < 2; ks2++) {
      int ksg = h * 2 + ks2;            // global k-step 0..3
      int kk0 = ks2 * 32;
      short8 ahi0, alo0, ahi1, alo1;
      if (amode == 2) {
        half8 a0 = *(const half8*)(Xh + rc0 * D + ksg * 32 + q * 8);
        half8 a1 = *(const half8*)(Xh + rc1 * D + ksg * 32 + q * 8);
#pragma unroll
        for (int j = 0; j < 8; j++) {
          float v = (float)a0[j];
          short hi = f2bf(v);
          ahi0[j] = hi; alo0[j] = f2bf(v - bf2f(hi));
          v = (float)a1[j];
          hi = f2bf(v);
          ahi1[j] = hi; alo1[j] = f2bf(v - bf2f(hi));
        }
      } else {
        const floatx4* x0 = (const floatx4*)(Xf + rc0 * D);
        const floatx4* x1 = (const floatx4*)(Xf + rc1 * D);
        int xi = ksg * 8 + q * 2;
        floatx4 a0 = x0[xi], a0b = x0[xi + 1];
        floatx4 a1 = x1[xi], a1b = x1[xi + 1];
#pragma unroll
        for (int j = 0; j < 4; j++) {
          float v = a0[j];  short hi = f2bf(v);
          ahi0[j] = hi; alo0[j] = f2bf(v - bf2f(hi));
          v = a0b[j]; hi = f2bf(v);
          ahi0[4 + j] = hi; alo0[4 + j] = f2bf(v - bf2f(hi));
          v = a1[j];  hi = f2bf(v);
          ahi1[j] = hi; alo1[j] = f2bf(v - bf2f(hi));
          v = a1b[j]; hi = f2bf(v);
          ahi1[4 + j] = hi; alo1[4 + j] = f2bf(v - bf2f(hi));
        }
      }
#pragma unroll
      for (int ct = 0; ct < 8; ct++) {
        int c = ct * 16 + r;
        short8 bh = *(const short8*)&wthi[c * 72 + kk0 + q * 8];
        short8 bl = *(const short8*)&wtlo[c * 72 + kk0 + q * 8];
        acc[0][ct] = __builtin_amdgcn_mfma_f32_16x16x32_bf16(ahi0, bh, acc[0][ct], 0, 0, 0);
        acc[0][ct] = __builtin_amdgcn_mfma_f32_16x16x32_bf16(alo0, bh, acc[0][ct], 0, 0, 0);
        acc[0][ct] = __builtin_amdgcn_mfma_f32_16x16x32_bf16(ahi0, bl, acc[0][ct], 0, 0, 0);
        acc[1][ct] = __builtin_amdgcn_mfma_f32_16x16x32_bf16(ahi1, bh, acc[1][ct], 0, 0, 0);
        acc[1][ct] = __builtin_amdgcn_mfma_f32_16x16x32_bf16(alo1, bh, acc[1][ct], 0, 0, 0);
        acc[1][ct] = __builtin_amdgcn_mfma_f32_16x16x32_bf16(ahi1, bl, acc[1][ct], 0, 0, 0);
      }
    }
  }

  // epilogue: C/D layout col = lane&15, row = q*4 + reg; fp16 out
#pragma unroll
  for (int rt = 0; rt < 2; rt++) {
#pragma unroll
    for (int i = 0; i < 4; i++) {
      long row = rowbase + rt * 16 + q * 4 + i;
      if (row < n) {
#pragma unroll
        for (int ct = 0; ct < 8; ct++) {
          int col = ct * 16 + r;
          float v = acc[rt][ct][i];
          if (bias) v += bias[col];
          if (act == 1) v = elu1(v);
          Yh[row * D + col] = (_Float16)v;
        }
      }
    }
  }
}

// ---------------- aggregation ----------------
// Y[d] = relu(sum_{e: dst=d} T[src]*norm + T[d]*dis[d]^2 + b)
// R3: 4 nodes per wave, 16 lanes per node, 16 B/lane half8 gathers.
// One gather instruction fetches 4 rows (4 edges) vs 1 before; per-edge
// address VALU ~4x lower; 16 rows in flight per wave (4 groups x unroll 4).
// Divergence only across the 4 groups (intra-group c is uniform).

__global__ __launch_bounds__(256) void k_agg(const _Float16* __restrict__ T,
                                             const int* __restrict__ rowptr,
                                             const int* __restrict__ counts,
                                             const int2* __restrict__ cpack,
                                             const float* __restrict__ dis,
                                             const float* __restrict__ bias,
                                             _Float16* __restrict__ Yh,
                                             float* __restrict__ Yf, int n) {
  int tid = threadIdx.x;
  int wave = tid >> 6;
  int lane = tid & 63;
  int g = lane >> 4;            // node group within wave (0..3)
  int r16 = lane & 15;          // lane within group; covers cols r16*8..r16*8+7
  int node = blockIdx.x * 16 + wave * 4 + g;
  bool actv = node < n;
  int nodec = actv ? node : 0;

  const half8* T8 = (const half8*)T;

  int s = actv ? rowptr[nodec] : 0;
  int c = actv ? counts[nodec] : 0;
  float dv = actv ? dis[nodec] : 0.f;
  float dv2 = dv * dv;

  half8 t = T8[(size_t)nodec * 16 + r16];
  float acc[8];
#pragma unroll
  for (int k = 0; k < 8; k++) acc[k] = (float)t[k] * dv2;

  int j = 0;
  for (; j + 3 < c; j += 4) {
    int2 m0 = cpack[s + j];
    int2 m1 = cpack[s + j + 1];
    int2 m2 = cpack[s + j + 2];
    int2 m3 = cpack[s + j + 3];
    half8 v0 = T8[(size_t)m0.x * 16 + r16];
    half8 v1 = T8[(size_t)m1.x * 16 + r16];
    half8 v2 = T8[(size_t)m2.x * 16 + r16];
    half8 v3 = T8[(size_t)m3.x * 16 + r16];
    float n0 = __int_as_float(m0.y), n1 = __int_as_float(m1.y);
    float n2 = __int_as_float(m2.y), n3 = __int_as_float(m3.y);
#pragma unroll
    for (int k = 0; k < 8; k++) {
      acc[k] += (float)v0[k] * n0;
      acc[k] += (float)v1[k] * n1;
      acc[k] += (float)v2[k] * n2;
      acc[k] += (float)v3[k] * n3;
    }
  }
  for (; j < c; ++j) {
    int2 m = cpack[s + j];
    half8 v = T8[(size_t)m.x * 16 + r16];
    float nw = __int_as_float(m.y);
#pragma unroll
    for (int k = 0; k < 8; k++) acc[k] += (float)v[k] * nw;
  }

  if (actv) {
    const floatx4* b4 = (const floatx4*)(bias + r16 * 8);
    floatx4 bb0 = b4[0], bb1 = b4[1];
    half8 oh;
    float of[8];
#pragma unroll
    for (int k = 0; k < 8; k++) {
      float bv = (k < 4) ? bb0[k] : bb1[k - 4];
      float o = fmaxf(acc[k] + bv, 0.f);
      of[k] = o;
      oh[k] = (_Float16)o;
    }
    *(half8*)&Yh[(size_t)node * D + r16 * 8] = oh;
    if (Yf) {
      floatx4 o0 = {of[0], of[1], of[2], of[3]};
      floatx4 o1 = {of[4], of[5], of[6], of[7]};
      floatx4* yp = (floatx4*)(Yf + (size_t)node * D + r16 * 8);
      yp[0] = o0;
      yp[1] = o1;
    }
  }
}

// ---------------- MLP head ----------------

__global__ __launch_bounds__(256) void k_head(const _Float16* __restrict__ M,
                                              const short* __restrict__ Whi,
                                              const short* __restrict__ Wlo,
                                              const float* __restrict__ b,
                                              float* __restrict__ logits,
                                              float* __restrict__ probs, int n) {
  int tid = threadIdx.x;
  int wave = tid >> 6, lane = tid & 63;
  int q = lane >> 4, r = lane & 15;

  long rowbase = (long)blockIdx.x * 128 + wave * 32;
  long row0 = rowbase + r;
  long row1 = rowbase + 16 + r;
  long rc0 = row0 < n ? row0 : (n - 1);
  long rc1 = row1 < n ? row1 : (n - 1);

  floatx4 acc[2][3];
#pragma unroll
  for (int rt = 0; rt < 2; rt++)
#pragma unroll
    for (int ct = 0; ct < 3; ct++) acc[rt][ct] = (floatx4){0.f, 0.f, 0.f, 0.f};

#pragma unroll
  for (int ks = 0; ks < 4; ks++) {
    half8 a0 = *(const half8*)(M + rc0 * D + ks * 32 + q * 8);
    half8 a1 = *(const half8*)(M + rc1 * D + ks * 32 + q * 8);
    short8 ahi0, alo0, ahi1, alo1;
#pragma unroll
    for (int j = 0; j < 8; j++) {
      float v = (float)a0[j];
      short hi = f2bf(v);
      ahi0[j] = hi; alo0[j] = f2bf(v - bf2f(hi));
      v = (float)a1[j];
      hi = f2bf(v);
      ahi1[j] = hi; alo1[j] = f2bf(v - bf2f(hi));
    }
#pragma unroll
    for (int ct = 0; ct < 3; ct++) {
      int c = ct * 16 + r;
      short8 bh = *(const short8*)&Whi[c * D + ks * 32 + q * 8];
      short8 bl = *(const short8*)&Wlo[c * D + ks * 32 + q * 8];
      acc[0][ct] = __builtin_amdgcn_mfma_f32_16x16x32_bf16(ahi0, bh, acc[0][ct], 0, 0, 0);
      acc[0][ct] = __builtin_amdgcn_mfma_f32_16x16x32_bf16(alo0, bh, acc[0][ct], 0, 0, 0);
      acc[0][ct] = __builtin_amdgcn_mfma_f32_16x16x32_bf16(ahi0, bl, acc[0][ct], 0, 0, 0);
      acc[1][ct] = __builtin_amdgcn_mfma_f32_16x16x32_bf16(ahi1, bh, acc[1][ct], 0, 0, 0);
      acc[1][ct] = __builtin_amdgcn_mfma_f32_16x16x32_bf16(alo1, bh, acc[1][ct], 0, 0, 0);
      acc[1][ct] = __builtin_amdgcn_mfma_f32_16x16x32_bf16(ahi1, bl, acc[1][ct], 0, 0, 0);
    }
  }

  float bb0 = b[r];
  float bb1 = b[16 + r];
  float bb2 = (r < 8) ? b[32 + r] : 0.f;

#pragma unroll
  for (int rt = 0; rt < 2; rt++) {
#pragma unroll
    for (int i = 0; i < 4; i++) {
      long row = rowbase + rt * 16 + q * 4 + i;
      float v0 = acc[rt][0][i] + bb0;
      float v1 = acc[rt][1][i] + bb1;
      float v2 = (r < 8) ? (acc[rt][2][i] + bb2) : -INFINITY;
      float mx = fmaxf(fmaxf(v0, v1), v2);
      mx = fmaxf(mx, __shfl_xor(mx, 1));
      mx = fmaxf(mx, __shfl_xor(mx, 2));
      mx = fmaxf(mx, __shfl_xor(mx, 4));
      mx = fmaxf(mx, __shfl_xor(mx, 8));
      float e0 = expf(v0 - mx);
      float e1 = expf(v1 - mx);
      float e2 = (r < 8) ? expf(v2 - mx) : 0.f;
      float sm = e0 + e1 + e2;
      sm += __shfl_xor(sm, 1);
      sm += __shfl_xor(sm, 2);
      sm += __shfl_xor(sm, 4);
      sm += __shfl_xor(sm, 8);
      float inv = 1.f / sm;
      if (row < n) {
        float* lp = logits + row * 40;
        float* pp = probs + row * 40;
        lp[r] = v0;      pp[r] = e0 * inv;
        lp[16 + r] = v1; pp[16 + r] = e1 * inv;
        if (r < 8) { lp[32 + r] = v2; pp[32 + r] = e2 * inv; }
      }
    }
  }
}

// ---------------- launcher ----------------

extern "C" void kernel_launch(void* const* d_in, const int* in_sizes, int n_in,
                              void* d_out, int out_size, void* d_ws, size_t ws_size,
                              hipStream_t stream) {
  const float* x   = (const float*)d_in[0];
  const int*   ei  = (const int*)d_in[1];
  const float* W1  = (const float*)d_in[2];
  const float* b1  = (const float*)d_in[3];
  const float* W2  = (const float*)d_in[4];
  const float* b2  = (const float*)d_in[5];
  const float* W3  = (const float*)d_in[6];
  const float* b3  = (const float*)d_in[7];
  const float* Wm1 = (const float*)d_in[8];
  const float* bm1 = (const float*)d_in[9];
  const float* Wm2 = (const float*)d_in[10];
  const float* bm2 = (const float*)d_in[11];

  int N = in_sizes[0] / D;
  int E = in_sizes[1] / 2;
  const int* srcp = ei;
  const int* dstp = ei + E;
  int NBIN = (N + BINW - 1) / BINW;

  char* w = (char*)d_ws;
  auto alloc = [&](size_t bytes) -> char* {
    char* p = w;
    w += (bytes + 255) & ~(size_t)255;
    return p;
  };
  int*   counts = (int*)alloc((size_t)N * 4);
  int*   rowptr = (int*)alloc((size_t)N * 4);
  float* dis    = (float*)alloc((size_t)N * 4);
  int*   bsum   = (int*)alloc(1024);
  int*   gbinc  = (int*)alloc(MAXBIN * 4);
  int*   binoff = (int*)alloc((MAXBIN + 1) * 4);
  int*   gbincur= (int*)alloc(MAXBIN * 4);
  short* wsplit = (short*)alloc(4 * 32768 * 2);
  short* w2hi   = (short*)alloc(6144 * 2);
  short* w2lo   = (short*)alloc(6144 * 2);
  int2*  cpack  = (int2*)alloc((size_t)E * 8);
  _Float16* tmp_h  = (_Float16*)alloc((size_t)N * D * 2);
  _Float16* hbuf_h = (_Float16*)alloc((size_t)N * D * 2);
  // staging (E x 4B) aliases tmp_h: dead until the first GEMM writes it,
  // and passB2 (last reader) precedes that in stream order.
  unsigned* staging = (unsigned*)tmp_h;

  float* logits = (float*)d_out;
  float* probs  = logits + (size_t)N * 40;
  float* emb    = probs + (size_t)N * 40;

  // weight pre-split
  k_prep<<<(65536 + 6144 + 255) / 256, 256, 0, stream>>>(W1, W2, W3, Wm1, Wm2,
                                                         wsplit, w2hi, w2lo);
  // CSR build: bin-hist -> scan -> bin-sort -> node-hist -> scan -> bin-sort2
  k_zero<<<(NBIN + 255) / 256, 256, 0, stream>>>(gbinc, NBIN);
  k_binhist<<<256, 256, 0, stream>>>(dstp, gbinc, E, NBIN);
  k_binscan<<<1, 256, 0, stream>>>(gbinc, binoff, gbincur, NBIN);
  k_passA<<<(E + ACHUNK - 1) / ACHUNK, 256, 0, stream>>>(srcp, dstp, gbincur,
                                                         staging, E, NBIN);
  k_nodehist<<<NBIN, 256, 0, stream>>>(staging, binoff, counts, N);
  int nb = (N + 1023) / 1024;
  k_scan1<<<nb, 256, 0, stream>>>(counts, rowptr, bsum, N);
  k_scan2<<<1, 256, 0, stream>>>(bsum, nb);
  k_finish<<<(N + 255) / 256, 256, 0, stream>>>(rowptr, dis, counts, bsum, N);
  k_passB2<<<NBIN, 256, 0, stream>>>(staging, binoff, rowptr, dis, cpack, N);

  int gblocks = (N + 127) / 128;
  int ablocks = (N + 15) / 16;
  const short* Whi1 = wsplit;
  const short* Wlo1 = wsplit + 16384;
  const short* Whi2 = wsplit + 32768;
  const short* Wlo2 = wsplit + 32768 + 16384;
  const short* Whi3 = wsplit + 2 * 32768;
  const short* Wlo3 = wsplit + 2 * 32768 + 16384;
  const short* Whm1 = wsplit + 3 * 32768;
  const short* Wlm1 = wsplit + 3 * 32768 + 16384;

  // layer 1 (fp32 A)
  k_gemm<<<gblocks, 256, 0, stream>>>(x, nullptr, Whi1, Wlo1, nullptr,
                                      tmp_h, N, 0, 0);
  k_agg<<<ablocks, 256, 0, stream>>>(tmp_h, rowptr, counts, cpack, dis, b1,
                                     hbuf_h, nullptr, N);
  // layer 2 (fp16 A)
  k_gemm<<<gblocks, 256, 0, stream>>>(nullptr, hbuf_h, Whi2, Wlo2, nullptr,
                                      tmp_h, N, 0, 2);
  k_agg<<<ablocks, 256, 0, stream>>>(tmp_h, rowptr, counts, cpack, dis, b2,
                                     hbuf_h, nullptr, N);
  // layer 3 -> emb (fp16 + fp32)
  k_gemm<<<gblocks, 256, 0, stream>>>(nullptr, hbuf_h, Whi3, Wlo3, nullptr,
                                      tmp_h, N, 0, 2);
  k_agg<<<ablocks, 256, 0, stream>>>(tmp_h, rowptr, counts, cpack, dis, b3,
                                     hbuf_h, emb, N);
  // MLP hidden (fp16 A, ELU, fp16 out)
  k_gemm<<<gblocks, 256, 0, stream>>>(nullptr, hbuf_h, Whm1, Wlm1, bm1,
                                      tmp_h, N, 1, 2);
  // head (fp16 A)
  k_head<<<gblocks, 256, 0, stream>>>(tmp_h, w2hi, w2lo, bm2,
                                      logits, probs, N);
}